// Round 8
// baseline (234.526 us; speedup 1.0000x reference)
//
#include <hip/hip_runtime.h>
#include <hip/hip_bf16.h>

#define N_NODES 50000
#define N_EDGES 800000
#define D_IN    512
#define D_OUT   256
#define NBLK_SCAN ((N_NODES + 1023) / 1024)   // 49
#define GEMM_NWG (((N_NODES + 127) / 128) * 2)  // 782
#define GEMM_Q   (GEMM_NWG / 8)                  // 97
#define GEMM_R   (GEMM_NWG % 8)                  // 6

typedef short s8v  __attribute__((ext_vector_type(8)));
typedef float f32x4 __attribute__((ext_vector_type(4)));

__device__ __forceinline__ unsigned short bf16b(float f) {
    __hip_bfloat16 h = __float2bfloat16(f);
    return *reinterpret_cast<unsigned short*>(&h);
}
__device__ __forceinline__ float bflo(unsigned u) { return __uint_as_float(u << 16); }
__device__ __forceinline__ float bfhi(unsigned u) { return __uint_as_float(u & 0xffff0000u); }

// global -> LDS direct copy, 16B per lane; LDS dest is wave-uniform base + lane*16
#define GLD16(gp, lp)                                                           \
    __builtin_amdgcn_global_load_lds(                                           \
        (const __attribute__((address_space(1))) unsigned int*)(const void*)(gp),\
        (__attribute__((address_space(3))) unsigned int*)(void*)(lp), 16, 0, 0)

__device__ __forceinline__ int wave_incl_scan(int v, int lane) {
    #pragma unroll
    for (int d = 1; d < 64; d <<= 1) {
        int u = __shfl_up(v, d, 64);
        if (lane >= d) v += u;
    }
    return v;
}

// ============ CSR build ============

__global__ void k_count(const int* __restrict__ col, int* __restrict__ cnt) {
    int i = blockIdx.x * 256 + threadIdx.x;
    if (i < N_EDGES) atomicAdd(&cnt[col[i]], 1);
}

__launch_bounds__(256)
__global__ void k_scan1(const int* __restrict__ cnt, int* __restrict__ bsum) {
    const int t = threadIdx.x, b = blockIdx.x;
    const int idx = b * 1024 + t * 4;
    int4 v = make_int4(0, 0, 0, 0);
    if (idx < N_NODES) v = *(const int4*)&cnt[idx];
    int s = v.x + v.y + v.z + v.w;
    #pragma unroll
    for (int d = 1; d < 64; d <<= 1) s += __shfl_xor(s, d, 64);
    __shared__ int ws[4];
    if ((t & 63) == 0) ws[t >> 6] = s;
    __syncthreads();
    if (t == 0) bsum[b] = ws[0] + ws[1] + ws[2] + ws[3];
}

__global__ void k_scan2(const int* __restrict__ bsum, int* __restrict__ boff) {
    const int t = threadIdx.x;   // 64
    int v = (t < NBLK_SCAN) ? bsum[t] : 0;
    int inc = wave_incl_scan(v, t);
    if (t < NBLK_SCAN) boff[t] = inc - v;
}

__launch_bounds__(256)
__global__ void k_scan3(const int* __restrict__ cnt, const int* __restrict__ boff,
                        int* __restrict__ row_ptr, float* __restrict__ dinv,
                        int* __restrict__ cursor) {
    const int t = threadIdx.x, b = blockIdx.x;
    const int lane = t & 63, wv = t >> 6;
    const int idx = b * 1024 + t * 4;
    int4 v = make_int4(0, 0, 0, 0);
    if (idx < N_NODES) v = *(const int4*)&cnt[idx];
    int s = v.x + v.y + v.z + v.w;
    int isc = wave_incl_scan(s, lane);
    __shared__ int wsum[4];
    if (lane == 63) wsum[wv] = isc;
    __syncthreads();
    int off = boff[b];
    #pragma unroll
    for (int i = 0; i < 4; ++i)
        if (i < wv) off += wsum[i];
    int p0 = off + isc - s;
    int p1 = p0 + v.x;
    int p2 = p1 + v.y;
    int p3 = p2 + v.z;
    if (idx < N_NODES) {
        row_ptr[idx + 0] = p0; cursor[idx + 0] = p0; dinv[idx + 0] = rsqrtf(1.f + (float)v.x);
        row_ptr[idx + 1] = p1; cursor[idx + 1] = p1; dinv[idx + 1] = rsqrtf(1.f + (float)v.y);
        row_ptr[idx + 2] = p2; cursor[idx + 2] = p2; dinv[idx + 2] = rsqrtf(1.f + (float)v.z);
        row_ptr[idx + 3] = p3; cursor[idx + 3] = p3; dinv[idx + 3] = rsqrtf(1.f + (float)v.w);
    }
    if (b == 0 && t == 0) row_ptr[N_NODES] = N_EDGES;
}

__global__ void k_fill(const int* __restrict__ row, const int* __restrict__ col,
                       int* __restrict__ cursor, int* __restrict__ csr_src) {
    int i = blockIdx.x * 256 + threadIdx.x;
    if (i < N_EDGES) {
        int pos = atomicAdd(&cursor[col[i]], 1);
        csr_src[pos] = row[i];
    }
}

// ============ W transpose + bf16 convert ============
__global__ void k_wt(const float* __restrict__ W, unsigned short* __restrict__ Wt) {
    int k = blockIdx.x;      // 512
    int n = threadIdx.x;     // 256
    Wt[(size_t)n * D_IN + k] = bf16b(W[(size_t)k * D_OUT + n]);
}

// ============ MFMA GEMM: yb = bf16(dinv[r] * (x @ W)) ============
// fp32 A staged direct via global_load_lds (32B-chunk XOR swizzle pre-applied on
// source address, LDS dest linear); fp32->bf16 convert on the ds_read side;
// dinv applied in fp32 epilogue. No reg staging -> no spill risk.
__launch_bounds__(256)
__global__ void k_gemm(const float* __restrict__ A,            // [N_NODES,512] fp32
                       const unsigned short* __restrict__ Wt,  // [256,512] bf16
                       const float* __restrict__ dinv,
                       unsigned short* __restrict__ yb)        // [N_NODES,256] bf16
{
    __shared__ __align__(16) float          As[128 * 64];   // 32 KB, [m][64k] fp32
    __shared__ __align__(16) unsigned short Bs[128 * 64];   // 16 KB, [n][64k] bf16

    // bijective XCD swizzle (m204)
    int orig = blockIdx.x;
    int xcd = orig % 8, pos = orig / 8;
    int wg = (xcd < GEMM_R) ? xcd * (GEMM_Q + 1) + pos
                            : GEMM_R * (GEMM_Q + 1) + (xcd - GEMM_R) * GEMM_Q + pos;
    const int nt = wg & 1;
    const int mt = wg >> 1;
    const int m0 = mt * 128;
    const int n0 = nt * 128;

    const int t  = threadIdx.x;
    const int w  = t >> 6;
    const int l  = t & 63;
    const int wm = (w >> 1) * 64;
    const int wn = (w & 1) * 64;
    const int lr = l & 15;
    const int lk = l >> 4;

    // ---- A staging: wave-load i covers rows rowbase=w*32+i*4..+3 (1KB linear).
    // lane l -> row rowbase+(l>>4), dest 32B-chunk (l&15)>>1, half l&1;
    // source 32B-chunk = destchunk ^ (row&7)  (inverse-swizzle on source, #21)
    const int arow_l = l >> 4;       // 0..3
    const int c32    = (l & 15) >> 1;
    size_t aoff[8];
    #pragma unroll
    for (int i = 0; i < 8; ++i) {
        int row = m0 + w * 32 + i * 4 + arow_l;
        if (row >= N_NODES) row = 0;             // tail clamp; outputs guarded
        int sc32 = c32 ^ (row & 7);
        aoff[i] = (size_t)row * D_IN + sc32 * 8 + (l & 1) * 4;   // float units
    }
    // ---- B staging (bf16, 16B-chunk swizzle, as round 7) ----
    const int srow = l >> 3;
    const int srcj = (l & 7) ^ srow;
    size_t boff[4];
    #pragma unroll
    for (int i = 0; i < 4; ++i) {
        int g = w * 4 + i;
        int bn = n0 + g * 8 + srow;
        boff[i] = (size_t)bn * D_IN + srcj * 8;
    }

    f32x4 acc[4][4] = {};

    for (int kk = 0; kk < D_IN; kk += 64) {
        #pragma unroll
        for (int i = 0; i < 8; ++i)
            GLD16(&A[aoff[i] + kk], (char*)As + (w * 32 + i * 4) * 256);
        #pragma unroll
        for (int i = 0; i < 4; ++i)
            GLD16(&Wt[boff[i] + kk], (char*)Bs + (w * 4 + i) * 1024);
        __syncthreads();

        #pragma unroll
        for (int ks = 0; ks < 2; ++ks) {
            s8v af[4], bfr[4];
            #pragma unroll
            for (int f = 0; f < 4; ++f) {
                int row = wm + f * 16 + lr;
                int ch  = (ks * 4 + lk) ^ (lr & 7);      // 32B chunk, swizzled
                const char* p = (const char*)As + row * 256 + ch * 32;
                float4 x0 = *(const float4*)p;
                float4 x1 = *(const float4*)(p + 16);
                union { s8v v; unsigned short h[8]; } u;
                u.h[0] = bf16b(x0.x); u.h[1] = bf16b(x0.y);
                u.h[2] = bf16b(x0.z); u.h[3] = bf16b(x0.w);
                u.h[4] = bf16b(x1.x); u.h[5] = bf16b(x1.y);
                u.h[6] = bf16b(x1.z); u.h[7] = bf16b(x1.w);
                af[f] = u.v;
            }
            const int kb = (ks * 64 + lk * 16) ^ ((lr & 7) << 4);
            #pragma unroll
            for (int f = 0; f < 4; ++f)
                bfr[f] = *(const s8v*)((const char*)Bs + ((wn + f * 16 + lr) * 128 + kb));
            #pragma unroll
            for (int fm = 0; fm < 4; ++fm)
                #pragma unroll
                for (int fn = 0; fn < 4; ++fn)
                    acc[fm][fn] = __builtin_amdgcn_mfma_f32_16x16x32_bf16(
                        af[fm], bfr[fn], acc[fm][fn], 0, 0, 0);
        }
        __syncthreads();
    }

    #pragma unroll
    for (int fm = 0; fm < 4; ++fm) {
        #pragma unroll
        for (int j = 0; j < 4; ++j) {
            int row = m0 + wm + fm * 16 + lk * 4 + j;
            if (row < N_NODES) {
                float s = dinv[row];
                #pragma unroll
                for (int fn = 0; fn < 4; ++fn) {
                    int col = n0 + wn + fn * 16 + lr;
                    yb[(size_t)row * D_OUT + col] = bf16b(acc[fm][fn][j] * s);
                }
            }
        }
    }
}

// ============ gather: out[c] = relu(dinv[c]*(yb[c] + sum yb[src]) + b) ============
// One node per wave; lane owns 4 cols (uint2 = 8B, 64 lanes = full 512B row).
// Edge loop in masked rounds of 16: all 16 row-loads issued back-to-back (MLP),
// accumulate under wave-uniform predication. No cross-lane combine needed.
__launch_bounds__(256)
__global__ void k_gather(const int* __restrict__ row_ptr, const int* __restrict__ csr_src,
                         const unsigned short* __restrict__ yb, const float* __restrict__ dinv,
                         const float* __restrict__ bias, float* __restrict__ out)
{
    const int c = blockIdx.x * 4 + (threadIdx.x >> 6);
    const int l = threadIdx.x & 63;
    const uint2* y2 = (const uint2*)yb;          // 64 uint2 per row

    uint2 sv = y2[(size_t)c * 64 + l];           // self-loop term
    float acc0 = bflo(sv.x), acc1 = bfhi(sv.x);
    float acc2 = bflo(sv.y), acc3 = bfhi(sv.y);

    const int s = row_ptr[c];
    const int e = row_ptr[c + 1];

    for (int i = s; i < e; i += 16) {
        int idx[16];
        #pragma unroll
        for (int j = 0; j < 16; ++j) {
            int p = i + j;
            idx[j] = csr_src[p < e ? p : e - 1];
        }
        uint2 v[16];
        #pragma unroll
        for (int j = 0; j < 16; ++j)
            v[j] = y2[(size_t)idx[j] * 64 + l];
        #pragma unroll
        for (int j = 0; j < 16; ++j) {
            if (i + j < e) {                     // wave-uniform branch
                acc0 += bflo(v[j].x); acc1 += bfhi(v[j].x);
                acc2 += bflo(v[j].y); acc3 += bfhi(v[j].y);
            }
        }
    }

    const float sc = dinv[c];
    float4 bb = ((const float4*)bias)[l];
    float4 o;
    o.x = fmaxf(fmaf(acc0, sc, bb.x), 0.f);
    o.y = fmaxf(fmaf(acc1, sc, bb.y), 0.f);
    o.z = fmaxf(fmaf(acc2, sc, bb.z), 0.f);
    o.w = fmaxf(fmaf(acc3, sc, bb.w), 0.f);
    ((float4*)out)[(size_t)c * 64 + l] = o;
}

extern "C" void kernel_launch(void* const* d_in, const int* in_sizes, int n_in,
                              void* d_out, int out_size, void* d_ws, size_t ws_size,
                              hipStream_t stream) {
    const float* x   = (const float*)d_in[0];
    const int*   ei  = (const int*)d_in[1];
    const float* W   = (const float*)d_in[2];
    const float* b   = (const float*)d_in[3];
    float*       out = (float*)d_out;

    const int* row = ei;
    const int* col = ei + N_EDGES;

    char* p = (char*)d_ws;
    unsigned short* yb = (unsigned short*)p;  p += (size_t)N_NODES * D_OUT * 2;   // 25.6 MB
    unsigned short* Wt = (unsigned short*)p;  p += (size_t)D_OUT * D_IN * 2;      // 256 KB
    int*   csr_src = (int*)p;                 p += (size_t)N_EDGES * 4;           // 3.2 MB
    int*   cnt     = (int*)p;                 p += (size_t)N_NODES * 4;
    int*   row_ptr = (int*)p;                 p += (size_t)(N_NODES + 4) * 4;
    int*   cursor  = (int*)p;                 p += (size_t)N_NODES * 4;
    float* dinv    = (float*)p;               p += (size_t)N_NODES * 4;
    int*   bsum    = (int*)p;                 p += (size_t)NBLK_SCAN * 4;
    int*   boff    = (int*)p;                 p += (size_t)NBLK_SCAN * 4;

    hipMemsetAsync(cnt, 0, (size_t)N_NODES * sizeof(int), stream);
    k_count<<<(N_EDGES + 255) / 256, 256, 0, stream>>>(col, cnt);
    k_scan1<<<NBLK_SCAN, 256, 0, stream>>>(cnt, bsum);
    k_scan2<<<1, 64, 0, stream>>>(bsum, boff);
    k_scan3<<<NBLK_SCAN, 256, 0, stream>>>(cnt, boff, row_ptr, dinv, cursor);
    k_fill <<<(N_EDGES + 255) / 256, 256, 0, stream>>>(row, col, cursor, csr_src);
    k_wt   <<<D_IN, D_OUT, 0, stream>>>(W, Wt);

    k_gemm<<<GEMM_NWG, 256, 0, stream>>>(x, Wt, dinv, yb);

    k_gather<<<N_NODES / 4, 256, 0, stream>>>(row_ptr, csr_src, yb, dinv, b, out);
}

// Round 9
// 207.063 us; speedup vs baseline: 1.1326x; 1.1326x over previous
//
#include <hip/hip_runtime.h>
#include <hip/hip_bf16.h>

#define N_NODES 50000
#define N_EDGES 800000
#define D_IN    512
#define D_OUT   256
#define NBLK_SCAN ((N_NODES + 1023) / 1024)   // 49
#define GEMM_NWG (((N_NODES + 127) / 128) * 2)  // 782
#define GEMM_Q   (GEMM_NWG / 8)                  // 97
#define GEMM_R   (GEMM_NWG % 8)                  // 6

typedef short s8v  __attribute__((ext_vector_type(8)));
typedef float f32x4 __attribute__((ext_vector_type(4)));

__device__ __forceinline__ unsigned short bf16b(float f) {
    __hip_bfloat16 h = __float2bfloat16(f);
    return *reinterpret_cast<unsigned short*>(&h);
}
__device__ __forceinline__ float bflo(unsigned u) { return __uint_as_float(u << 16); }
__device__ __forceinline__ float bfhi(unsigned u) { return __uint_as_float(u & 0xffff0000u); }

// global -> LDS direct copy, 16B per lane; LDS dest is wave-uniform base + lane*16
#define GLD16(gp, lp)                                                           \
    __builtin_amdgcn_global_load_lds(                                           \
        (const __attribute__((address_space(1))) unsigned int*)(const void*)(gp),\
        (__attribute__((address_space(3))) unsigned int*)(void*)(lp), 16, 0, 0)

__device__ __forceinline__ int wave_incl_scan(int v, int lane) {
    #pragma unroll
    for (int d = 1; d < 64; d <<= 1) {
        int u = __shfl_up(v, d, 64);
        if (lane >= d) v += u;
    }
    return v;
}

// ============ CSR build ============

__global__ void k_count(const int* __restrict__ col, int* __restrict__ cnt) {
    int i = blockIdx.x * 256 + threadIdx.x;
    if (i < N_EDGES) atomicAdd(&cnt[col[i]], 1);
}

__launch_bounds__(256)
__global__ void k_scan1(const int* __restrict__ cnt, int* __restrict__ bsum) {
    const int t = threadIdx.x, b = blockIdx.x;
    const int idx = b * 1024 + t * 4;
    int4 v = make_int4(0, 0, 0, 0);
    if (idx < N_NODES) v = *(const int4*)&cnt[idx];
    int s = v.x + v.y + v.z + v.w;
    #pragma unroll
    for (int d = 1; d < 64; d <<= 1) s += __shfl_xor(s, d, 64);
    __shared__ int ws[4];
    if ((t & 63) == 0) ws[t >> 6] = s;
    __syncthreads();
    if (t == 0) bsum[b] = ws[0] + ws[1] + ws[2] + ws[3];
}

__global__ void k_scan2(const int* __restrict__ bsum, int* __restrict__ boff) {
    const int t = threadIdx.x;   // 64
    int v = (t < NBLK_SCAN) ? bsum[t] : 0;
    int inc = wave_incl_scan(v, t);
    if (t < NBLK_SCAN) boff[t] = inc - v;
}

__launch_bounds__(256)
__global__ void k_scan3(const int* __restrict__ cnt, const int* __restrict__ boff,
                        int* __restrict__ row_ptr, float* __restrict__ dinv,
                        int* __restrict__ cursor) {
    const int t = threadIdx.x, b = blockIdx.x;
    const int lane = t & 63, wv = t >> 6;
    const int idx = b * 1024 + t * 4;
    int4 v = make_int4(0, 0, 0, 0);
    if (idx < N_NODES) v = *(const int4*)&cnt[idx];
    int s = v.x + v.y + v.z + v.w;
    int isc = wave_incl_scan(s, lane);
    __shared__ int wsum[4];
    if (lane == 63) wsum[wv] = isc;
    __syncthreads();
    int off = boff[b];
    #pragma unroll
    for (int i = 0; i < 4; ++i)
        if (i < wv) off += wsum[i];
    int p0 = off + isc - s;
    int p1 = p0 + v.x;
    int p2 = p1 + v.y;
    int p3 = p2 + v.z;
    if (idx < N_NODES) {
        row_ptr[idx + 0] = p0; cursor[idx + 0] = p0; dinv[idx + 0] = rsqrtf(1.f + (float)v.x);
        row_ptr[idx + 1] = p1; cursor[idx + 1] = p1; dinv[idx + 1] = rsqrtf(1.f + (float)v.y);
        row_ptr[idx + 2] = p2; cursor[idx + 2] = p2; dinv[idx + 2] = rsqrtf(1.f + (float)v.z);
        row_ptr[idx + 3] = p3; cursor[idx + 3] = p3; dinv[idx + 3] = rsqrtf(1.f + (float)v.w);
    }
    if (b == 0 && t == 0) row_ptr[N_NODES] = N_EDGES;
}

__global__ void k_fill(const int* __restrict__ row, const int* __restrict__ col,
                       int* __restrict__ cursor, int* __restrict__ csr_src) {
    int i = blockIdx.x * 256 + threadIdx.x;
    if (i < N_EDGES) {
        int pos = atomicAdd(&cursor[col[i]], 1);
        csr_src[pos] = row[i];
    }
}

// ============ W transpose + bf16 convert ============
__global__ void k_wt(const float* __restrict__ W, unsigned short* __restrict__ Wt) {
    int k = blockIdx.x;      // 512
    int n = threadIdx.x;     // 256
    Wt[(size_t)n * D_IN + k] = bf16b(W[(size_t)k * D_OUT + n]);
}

// ============ MFMA GEMM: yb = bf16(dinv[r] * (x @ W)) ============
// fp32 A staged via global_load_lds with 16B-SLOT-granularity XOR swizzle on the
// SOURCE address (round-8 lesson: 32B granularity left bank index = f(chunk&3)
// only -> 16-way conflicts; 16B slots XORed over all 8 bank-positions of a 128B
// line reproduce the R7 bf16 distribution that measured ZERO conflicts).
// Stored slot s of row r holds logical slot s ^ (r&7). Reads fetch logical 32B
// chunk c as stored slots {2c^(r&7), (2c+1)^(r&7)} = two independent b128 reads.
__launch_bounds__(256)
__global__ void k_gemm(const float* __restrict__ A,            // [N_NODES,512] fp32
                       const unsigned short* __restrict__ Wt,  // [256,512] bf16
                       const float* __restrict__ dinv,
                       unsigned short* __restrict__ yb)        // [N_NODES,256] bf16
{
    __shared__ __align__(16) float          As[128 * 64];   // 32 KB, [m][64k] fp32
    __shared__ __align__(16) unsigned short Bs[128 * 64];   // 16 KB, [n][64k] bf16

    // bijective XCD swizzle (m204)
    int orig = blockIdx.x;
    int xcd = orig % 8, pos = orig / 8;
    int wg = (xcd < GEMM_R) ? xcd * (GEMM_Q + 1) + pos
                            : GEMM_R * (GEMM_Q + 1) + (xcd - GEMM_R) * GEMM_Q + pos;
    const int nt = wg & 1;
    const int mt = wg >> 1;
    const int m0 = mt * 128;
    const int n0 = nt * 128;

    const int t  = threadIdx.x;
    const int w  = t >> 6;
    const int l  = t & 63;
    const int wm = (w >> 1) * 64;
    const int wn = (w & 1) * 64;
    const int lr = l & 15;
    const int lk = l >> 4;

    // ---- A staging: wave-load i covers rows rowbase=w*32+i*4..+3 (1KB linear).
    // lane l -> LDS row rowbase+(l>>4), dest 16B-slot l&15;
    // source 16B-slot = (l&15) ^ (row&7)
    size_t aoff[8];
    #pragma unroll
    for (int i = 0; i < 8; ++i) {
        int row = m0 + w * 32 + i * 4 + (l >> 4);
        if (row >= N_NODES) row = 0;             // tail clamp; outputs guarded
        int sslot = (l & 15) ^ (row & 7);
        aoff[i] = (size_t)row * D_IN + sslot * 4;   // float units (16B slot = 4 floats)
    }
    // ---- B staging (bf16, 16B-chunk swizzle, zero-conflict since R7) ----
    const int srow = l >> 3;
    const int srcj = (l & 7) ^ srow;
    size_t boff[4];
    #pragma unroll
    for (int i = 0; i < 4; ++i) {
        int g = w * 4 + i;
        int bn = n0 + g * 8 + srow;
        boff[i] = (size_t)bn * D_IN + srcj * 8;
    }

    f32x4 acc[4][4] = {};

    for (int kk = 0; kk < D_IN; kk += 64) {
        #pragma unroll
        for (int i = 0; i < 8; ++i)
            GLD16(&A[aoff[i] + kk], (char*)As + (w * 32 + i * 4) * 256);
        #pragma unroll
        for (int i = 0; i < 4; ++i)
            GLD16(&Wt[boff[i] + kk], (char*)Bs + (w * 4 + i) * 1024);
        __syncthreads();

        #pragma unroll
        for (int ks = 0; ks < 2; ++ks) {
            s8v af[4], bfr[4];
            #pragma unroll
            for (int f = 0; f < 4; ++f) {
                int row = wm + f * 16 + lr;           // row&7 == lr&7
                int a   = (ks * 4 + lk) * 2;          // logical 16B slot (even)
                int s0  = a ^ (lr & 7);
                int s1  = (a + 1) ^ (lr & 7);         // = s0 ^ 1
                const char* pr = (const char*)As + row * 256;
                float4 x0 = *(const float4*)(pr + s0 * 16);
                float4 x1 = *(const float4*)(pr + s1 * 16);
                union { s8v v; unsigned short h[8]; } u;
                u.h[0] = bf16b(x0.x); u.h[1] = bf16b(x0.y);
                u.h[2] = bf16b(x0.z); u.h[3] = bf16b(x0.w);
                u.h[4] = bf16b(x1.x); u.h[5] = bf16b(x1.y);
                u.h[6] = bf16b(x1.z); u.h[7] = bf16b(x1.w);
                af[f] = u.v;
            }
            const int kb = (ks * 64 + lk * 16) ^ ((lr & 7) << 4);
            #pragma unroll
            for (int f = 0; f < 4; ++f)
                bfr[f] = *(const s8v*)((const char*)Bs + ((wn + f * 16 + lr) * 128 + kb));
            #pragma unroll
            for (int fm = 0; fm < 4; ++fm)
                #pragma unroll
                for (int fn = 0; fn < 4; ++fn)
                    acc[fm][fn] = __builtin_amdgcn_mfma_f32_16x16x32_bf16(
                        af[fm], bfr[fn], acc[fm][fn], 0, 0, 0);
        }
        __syncthreads();
    }

    #pragma unroll
    for (int fm = 0; fm < 4; ++fm) {
        #pragma unroll
        for (int j = 0; j < 4; ++j) {
            int row = m0 + wm + fm * 16 + lk * 4 + j;
            if (row < N_NODES) {
                float s = dinv[row];
                #pragma unroll
                for (int fn = 0; fn < 4; ++fn) {
                    int col = n0 + wn + fn * 16 + lr;
                    yb[(size_t)row * D_OUT + col] = bf16b(acc[fm][fn][j] * s);
                }
            }
        }
    }
}

// ============ gather: out[c] = relu(dinv[c]*(yb[c] + sum yb[src]) + b) ============
// One node per wave; lane owns 4 cols (uint2 = 8B, 64 lanes = full 512B row).
// Tiered loop (round-8 lesson: clamped rounds of 16 wasted ~7.5 row-loads/node =
// ~190MB): unmasked full rounds of 16 (zero waste, 16 loads in flight), then a
// clamped tail in rounds of 4 (<=3 wasted loads/node).
__launch_bounds__(256)
__global__ void k_gather(const int* __restrict__ row_ptr, const int* __restrict__ csr_src,
                         const unsigned short* __restrict__ yb, const float* __restrict__ dinv,
                         const float* __restrict__ bias, float* __restrict__ out)
{
    const int c = blockIdx.x * 4 + (threadIdx.x >> 6);
    const int l = threadIdx.x & 63;
    const uint2* y2 = (const uint2*)yb;          // 64 uint2 per row

    uint2 sv = y2[(size_t)c * 64 + l];           // self-loop term
    float acc0 = bflo(sv.x), acc1 = bfhi(sv.x);
    float acc2 = bflo(sv.y), acc3 = bfhi(sv.y);

    const int s = row_ptr[c];
    const int e = row_ptr[c + 1];

    int i = s;
    while (i + 16 <= e) {                        // full rounds, no masking
        int idx[16];
        #pragma unroll
        for (int j = 0; j < 16; ++j) idx[j] = csr_src[i + j];
        uint2 v[16];
        #pragma unroll
        for (int j = 0; j < 16; ++j) v[j] = y2[(size_t)idx[j] * 64 + l];
        #pragma unroll
        for (int j = 0; j < 16; ++j) {
            acc0 += bflo(v[j].x); acc1 += bfhi(v[j].x);
            acc2 += bflo(v[j].y); acc3 += bfhi(v[j].y);
        }
        i += 16;
    }
    while (i < e) {                              // clamped tail, rounds of 4
        int idx[4];
        #pragma unroll
        for (int j = 0; j < 4; ++j) {
            int p = i + j;
            idx[j] = csr_src[p < e ? p : e - 1];
        }
        uint2 v[4];
        #pragma unroll
        for (int j = 0; j < 4; ++j) v[j] = y2[(size_t)idx[j] * 64 + l];
        #pragma unroll
        for (int j = 0; j < 4; ++j) {
            if (i + j < e) {                     // wave-uniform
                acc0 += bflo(v[j].x); acc1 += bfhi(v[j].x);
                acc2 += bflo(v[j].y); acc3 += bfhi(v[j].y);
            }
        }
        i += 4;
    }

    const float sc = dinv[c];
    float4 bb = ((const float4*)bias)[l];
    float4 o;
    o.x = fmaxf(fmaf(acc0, sc, bb.x), 0.f);
    o.y = fmaxf(fmaf(acc1, sc, bb.y), 0.f);
    o.z = fmaxf(fmaf(acc2, sc, bb.z), 0.f);
    o.w = fmaxf(fmaf(acc3, sc, bb.w), 0.f);
    ((float4*)out)[(size_t)c * 64 + l] = o;
}

extern "C" void kernel_launch(void* const* d_in, const int* in_sizes, int n_in,
                              void* d_out, int out_size, void* d_ws, size_t ws_size,
                              hipStream_t stream) {
    const float* x   = (const float*)d_in[0];
    const int*   ei  = (const int*)d_in[1];
    const float* W   = (const float*)d_in[2];
    const float* b   = (const float*)d_in[3];
    float*       out = (float*)d_out;

    const int* row = ei;
    const int* col = ei + N_EDGES;

    char* p = (char*)d_ws;
    unsigned short* yb = (unsigned short*)p;  p += (size_t)N_NODES * D_OUT * 2;   // 25.6 MB
    unsigned short* Wt = (unsigned short*)p;  p += (size_t)D_OUT * D_IN * 2;      // 256 KB
    int*   csr_src = (int*)p;                 p += (size_t)N_EDGES * 4;           // 3.2 MB
    int*   cnt     = (int*)p;                 p += (size_t)N_NODES * 4;
    int*   row_ptr = (int*)p;                 p += (size_t)(N_NODES + 4) * 4;
    int*   cursor  = (int*)p;                 p += (size_t)N_NODES * 4;
    float* dinv    = (float*)p;               p += (size_t)N_NODES * 4;
    int*   bsum    = (int*)p;                 p += (size_t)NBLK_SCAN * 4;
    int*   boff    = (int*)p;                 p += (size_t)NBLK_SCAN * 4;

    hipMemsetAsync(cnt, 0, (size_t)N_NODES * sizeof(int), stream);
    k_count<<<(N_EDGES + 255) / 256, 256, 0, stream>>>(col, cnt);
    k_scan1<<<NBLK_SCAN, 256, 0, stream>>>(cnt, bsum);
    k_scan2<<<1, 64, 0, stream>>>(bsum, boff);
    k_scan3<<<NBLK_SCAN, 256, 0, stream>>>(cnt, boff, row_ptr, dinv, cursor);
    k_fill <<<(N_EDGES + 255) / 256, 256, 0, stream>>>(row, col, cursor, csr_src);
    k_wt   <<<D_IN, D_OUT, 0, stream>>>(W, Wt);

    k_gemm<<<GEMM_NWG, 256, 0, stream>>>(x, Wt, dinv, yb);

    k_gather<<<N_NODES / 4, 256, 0, stream>>>(row_ptr, csr_src, yb, dinv, b, out);
}